// Round 4
// baseline (1599.357 us; speedup 1.0000x reference)
//
#include <hip/hip_runtime.h>
#include <cstdint>
#include <cstddef>

typedef uint16_t u16;
typedef __bf16 bf16x8 __attribute__((ext_vector_type(8)));
typedef float f32x4 __attribute__((ext_vector_type(4)));
typedef u16 u16x8 __attribute__((ext_vector_type(8)));

// ---- sizes (fixed) ----
// SEQ=2048 HIDDEN=4096 NQ=32 NKV=8 HD=128 WINDOW=1024
// Inputs are FLOAT32 (per reference setup_inputs); output FLOAT32.
// Intermediate qkv kept in bf16 (feeds bf16 MFMA attention).

__device__ __forceinline__ float bf2f(u16 u) {
    union { uint32_t i; float f; } v; v.i = ((uint32_t)u) << 16; return v.f;
}
__device__ __forceinline__ u16 f2bf(float f) {
    union { float f; uint32_t i; } v; v.f = f;
    uint32_t b = v.i;
    return (u16)((b + 0x7FFFu + ((b >> 16) & 1u)) >> 16);  // RNE
}
// NaN/inf localizer: replaces non-finite with a stage-specific sentinel.
__device__ __forceinline__ float nanfix(float x, float repl) {
    return (x == x && fabsf(x) < 1e30f) ? x : repl;
}

// ------- GEMM: C(M,N) = A(M,K) * B(K,N); A,B fp32 in HBM, bf16 MFMA compute ---
// A staged row-major, B transposed into LDS (stride 40). 128x128 tile, BK=32,
// 256 threads = 4 waves, wave = 64x64 (4x4 MFMA 16x16x32 tiles).
__global__ __launch_bounds__(256) void gemm_f32in(
    const float* __restrict__ A, const float* __restrict__ B, void* __restrict__ Cv,
    int M, int N, int K, int ldc, int out_f32, float nan_repl)
{
    alignas(16) __shared__ u16 As[128 * 32];
    alignas(16) __shared__ u16 Bs[128 * 40];   // [n][k] transposed, pad 40
    const int tid = threadIdx.x;
    const int wave = tid >> 6, lane = tid & 63;
    const int lr = lane & 15, qd = lane >> 4;
    const int m0 = blockIdx.y * 128, n0 = blockIdx.x * 128;
    const int wm = (wave >> 1) * 64, wn = (wave & 1) * 64;

    f32x4 acc[4][4];
    #pragma unroll
    for (int i = 0; i < 4; i++)
        #pragma unroll
        for (int j = 0; j < 4; j++) acc[i][j] = (f32x4){0.f, 0.f, 0.f, 0.f};

    const int i0 = tid * 8, i1 = i0 + 2048;
    const int r0 = i0 >> 5, c0 = i0 & 31;
    const int r1 = i1 >> 5, c1 = i1 & 31;
    const int bkr = tid >> 4, bnc = (tid & 15) * 8;  // B-tile stage coords

    for (int k0 = 0; k0 < K; k0 += 32) {
        {
            const f32x4* pa0 = (const f32x4*)&A[(size_t)(m0 + r0) * K + (k0 + c0)];
            const f32x4* pa1 = (const f32x4*)&A[(size_t)(m0 + r1) * K + (k0 + c1)];
            const f32x4 a00 = pa0[0], a01 = pa0[1], a10 = pa1[0], a11 = pa1[1];
            u16x8 s0, s1;
            #pragma unroll
            for (int e = 0; e < 4; e++) {
                s0[e] = f2bf(a00[e]); s0[4 + e] = f2bf(a01[e]);
                s1[e] = f2bf(a10[e]); s1[4 + e] = f2bf(a11[e]);
            }
            *(u16x8*)&As[i0] = s0;
            *(u16x8*)&As[i1] = s1;
        }
        #pragma unroll
        for (int p = 0; p < 2; p++) {
            const int kr = p * 16 + bkr;
            const f32x4* pb = (const f32x4*)&B[(size_t)(k0 + kr) * N + (n0 + bnc)];
            const f32x4 b0 = pb[0], b1 = pb[1];
            #pragma unroll
            for (int e = 0; e < 4; e++) {
                Bs[(bnc + e) * 40 + kr]     = f2bf(b0[e]);
                Bs[(bnc + 4 + e) * 40 + kr] = f2bf(b1[e]);
            }
        }
        __syncthreads();
        bf16x8 a[4], b[4];
        #pragma unroll
        for (int i = 0; i < 4; i++)
            a[i] = *(const bf16x8*)&As[(wm + i * 16 + lr) * 32 + qd * 8];
        #pragma unroll
        for (int i = 0; i < 4; i++)
            b[i] = *(const bf16x8*)&Bs[(wn + i * 16 + lr) * 40 + qd * 8];
        #pragma unroll
        for (int i = 0; i < 4; i++)
            #pragma unroll
            for (int j = 0; j < 4; j++)
                acc[i][j] = __builtin_amdgcn_mfma_f32_16x16x32_bf16(a[i], b[j], acc[i][j], 0, 0, 0);
        __syncthreads();
    }
    // C/D layout: col = lane&15, row = (lane>>4)*4 + reg  [verified m89/m91]
    #pragma unroll
    for (int i = 0; i < 4; i++)
        #pragma unroll
        for (int j = 0; j < 4; j++) {
            const int col = n0 + wn + j * 16 + lr;
            #pragma unroll
            for (int r = 0; r < 4; r++) {
                const int row = m0 + wm + i * 16 + qd * 4 + r;
                const float val = nanfix(acc[i][j][r], nan_repl);
                if (out_f32) ((float*)Cv)[(size_t)row * ldc + col] = val;
                else         ((u16*)Cv)[(size_t)row * ldc + col] = f2bf(val);
            }
        }
}

// ---------------- NeoX RoPE in-place on q (cols 0..4095) and k (4096..5119) ----
__global__ void rope_k(u16* __restrict__ qkv, const int* __restrict__ positions) {
    const int s = blockIdx.x;
    const int h = blockIdx.y;   // 0..39: 32 q heads then 8 k heads
    const int t = threadIdx.x;  // 0..63 (pair index)
    u16* base = qkv + (size_t)s * 6144 + ((h < 32) ? h * 128 : 4096 + (h - 32) * 128);
    const float pos = (float)positions[s];
    // inv_freq[t] = 1e6^(-t/64); log2(1e6) = 19.931568569324174
    const float freq = pos * exp2f(-(float)t * (19.931568569324174f / 64.f));
    const float c = cosf(freq), sn = sinf(freq);
    const float x1 = bf2f(base[t]), x2 = bf2f(base[t + 64]);
    base[t]      = f2bf(x1 * c - x2 * sn);
    base[t + 64] = f2bf(x2 * c + x1 * sn);
}

// ---------------- flash attention, window=1024, sink, GQA 4:1 ------------------
// grid: (q-tile=SEQ/64, head=32), 256 threads = 4 waves; wave owns 16 q-rows.
// qkv bf16 in, attn out fp32.
__global__ __launch_bounds__(256) void attn_k(
    const u16* __restrict__ qkv, const float* __restrict__ sink,
    float* __restrict__ out)
{
    alignas(16) __shared__ u16 Qs[64 * 128];
    alignas(16) __shared__ u16 Ks[64 * 128];
    alignas(16) __shared__ u16 VsT[128 * 72];   // V transposed, pad 72 (16B rows)
    alignas(16) __shared__ u16 Ps[4][16 * 64];  // per-wave P (C->A layout bridge)

    const int h = blockIdx.y, hk = h >> 2;
    const int q0 = blockIdx.x * 64;
    const int tid = threadIdx.x, wave = tid >> 6, lane = tid & 63;
    const int lr = lane & 15, qd = lane >> 4;
    const float scaling = 0.08838834764831845f;  // 1/sqrt(128)

    // stage Q tile (post-RoPE)
    #pragma unroll
    for (int base = 0; base < 8192; base += 2048) {
        const int idx = base + tid * 8;
        const int r = idx >> 7, c = idx & 127;
        *(u16x8*)&Qs[idx] = *(const u16x8*)&qkv[(size_t)(q0 + r) * 6144 + h * 128 + c];
    }

    const float sinkv = sink[h];
    float m_run[4], l_run[4];
    #pragma unroll
    for (int r = 0; r < 4; r++) { m_run[r] = sinkv; l_run[r] = 0.f; }
    f32x4 acc_o[8];
    #pragma unroll
    for (int i = 0; i < 8; i++) acc_o[i] = (f32x4){0.f, 0.f, 0.f, 0.f};

    const int jlo = (q0 - 1023) > 0 ? (q0 - 1023) : 0;
    const int t0 = jlo >> 6, t1 = q0 >> 6;

    for (int kt = t0; kt <= t1; kt++) {
        const int j0 = kt * 64;
        __syncthreads();  // WAR: prior-iter reads of Ks/VsT done (also orders Qs)
        #pragma unroll
        for (int base = 0; base < 8192; base += 2048) {
            const int idx = base + tid * 8;
            const int r = idx >> 7, c = idx & 127;
            *(u16x8*)&Ks[idx] = *(const u16x8*)&qkv[(size_t)(j0 + r) * 6144 + 4096 + hk * 128 + c];
            const u16x8 v = *(const u16x8*)&qkv[(size_t)(j0 + r) * 6144 + 5120 + hk * 128 + c];
            #pragma unroll
            for (int e = 0; e < 8; e++) VsT[(c + e) * 72 + r] = v[e];
        }
        __syncthreads();

        // S = Q K^T : per-wave 16x64, K=128 as 4 MFMA chunks
        bf16x8 aq[4];
        #pragma unroll
        for (int kc = 0; kc < 4; kc++)
            aq[kc] = *(const bf16x8*)&Qs[(wave * 16 + lr) * 128 + kc * 32 + qd * 8];
        float sv[4][4];
        #pragma unroll
        for (int nt = 0; nt < 4; nt++) {
            f32x4 s = (f32x4){0.f, 0.f, 0.f, 0.f};
            #pragma unroll
            for (int kc = 0; kc < 4; kc++) {
                const bf16x8 bk = *(const bf16x8*)&Ks[(nt * 16 + lr) * 128 + kc * 32 + qd * 8];
                s = __builtin_amdgcn_mfma_f32_16x16x32_bf16(aq[kc], bk, s, 0, 0, 0);
            }
            #pragma unroll
            for (int r = 0; r < 4; r++) sv[nt][r] = s[r];
        }

        // mask + scale + row max (row = qd*4+r, col = nt*16+lr)
        float rmax[4] = {-1e30f, -1e30f, -1e30f, -1e30f};
        #pragma unroll
        for (int nt = 0; nt < 4; nt++) {
            const int kpos = j0 + nt * 16 + lr;
            #pragma unroll
            for (int r = 0; r < 4; r++) {
                const int qpos = q0 + wave * 16 + qd * 4 + r;
                const bool ok = (kpos <= qpos) && (qpos - kpos < 1024);
                const float x = ok ? sv[nt][r] * scaling : -1e30f;
                sv[nt][r] = x;
                rmax[r] = fmaxf(rmax[r], x);
            }
        }
        #pragma unroll
        for (int off = 1; off < 16; off <<= 1)
            #pragma unroll
            for (int r = 0; r < 4; r++)
                rmax[r] = fmaxf(rmax[r], __shfl_xor(rmax[r], off, 64));

        float alpha[4], rsum[4];
        #pragma unroll
        for (int r = 0; r < 4; r++) {
            const float mnew = fmaxf(m_run[r], rmax[r]);
            alpha[r] = __expf(m_run[r] - mnew);
            m_run[r] = mnew;
            rsum[r] = 0.f;
        }
        #pragma unroll
        for (int nt = 0; nt < 4; nt++)
            #pragma unroll
            for (int r = 0; r < 4; r++) {
                const float p = __expf(sv[nt][r] - m_run[r]);
                sv[nt][r] = p;
                rsum[r] += p;
            }
        #pragma unroll
        for (int off = 1; off < 16; off <<= 1)
            #pragma unroll
            for (int r = 0; r < 4; r++)
                rsum[r] += __shfl_xor(rsum[r], off, 64);
        #pragma unroll
        for (int r = 0; r < 4; r++)
            l_run[r] = l_run[r] * alpha[r] + rsum[r];

        // P (C-layout) -> LDS; barrier before A-layout re-read.
        #pragma unroll
        for (int nt = 0; nt < 4; nt++)
            #pragma unroll
            for (int r = 0; r < 4; r++)
                Ps[wave][(qd * 4 + r) * 64 + nt * 16 + lr] = f2bf(sv[nt][r]);

        #pragma unroll
        for (int i = 0; i < 8; i++)
            #pragma unroll
            for (int r = 0; r < 4; r++) acc_o[i][r] *= alpha[r];

        __syncthreads();

        bf16x8 pa[2];
        #pragma unroll
        for (int kc = 0; kc < 2; kc++)
            pa[kc] = *(const bf16x8*)&Ps[wave][lr * 64 + kc * 32 + qd * 8];

        // O += P * V  (V B-frags contiguous from VsT)
        #pragma unroll
        for (int nt = 0; nt < 8; nt++)
            #pragma unroll
            for (int kc = 0; kc < 2; kc++) {
                const bf16x8 bv = *(const bf16x8*)&VsT[(nt * 16 + lr) * 72 + kc * 32 + qd * 8];
                acc_o[nt] = __builtin_amdgcn_mfma_f32_16x16x32_bf16(pa[kc], bv, acc_o[nt], 0, 0, 0);
            }
    }

    float invd[4];
    #pragma unroll
    for (int r = 0; r < 4; r++)
        invd[r] = 1.f / (l_run[r] + __expf(sinkv - m_run[r]));
    #pragma unroll
    for (int nt = 0; nt < 8; nt++) {
        const int col = h * 128 + nt * 16 + lr;
        #pragma unroll
        for (int r = 0; r < 4; r++) {
            const int row = q0 + wave * 16 + qd * 4 + r;
            out[(size_t)row * 4096 + col] = nanfix(acc_o[nt][r] * invd[r], 8.0f);
        }
    }
}

extern "C" void kernel_launch(void* const* d_in, const int* in_sizes, int n_in,
                              void* d_out, int out_size, void* d_ws, size_t ws_size,
                              hipStream_t stream)
{
    (void)in_sizes; (void)n_in; (void)out_size; (void)ws_size;
    const float* hidden    = (const float*)d_in[0];
    const int*   positions = (const int*)d_in[1];
    const float* wq   = (const float*)d_in[2];
    const float* wk   = (const float*)d_in[3];
    const float* wv   = (const float*)d_in[4];
    const float* wo   = (const float*)d_in[5];
    const float* sink = (const float*)d_in[6];
    float* out = (float*)d_out;

    // Workspace: qkv bf16 (2048x6144, 24 MB) + attn fp32 (2048x4096, 32 MB) = 56 MB
    char* ws = (char*)d_ws;
    u16*   qkv  = (u16*)(ws);
    float* attn = (float*)(ws + (size_t)25165824);

    // QKV projections (fp32 in, bf16 MFMA, bf16 out into qkv strided 6144)
    gemm_f32in<<<dim3(32, 16), 256, 0, stream>>>(hidden, wq, qkv,        2048, 4096, 4096, 6144, 0, 1000.0f);
    gemm_f32in<<<dim3(8,  16), 256, 0, stream>>>(hidden, wk, qkv + 4096, 2048, 1024, 4096, 6144, 0, 1000.0f);
    gemm_f32in<<<dim3(8,  16), 256, 0, stream>>>(hidden, wv, qkv + 5120, 2048, 1024, 4096, 6144, 0, 1000.0f);

    // RoPE on q + k columns
    rope_k<<<dim3(2048, 40), 64, 0, stream>>>(qkv, positions);
    // windowed flash attention with sink -> fp32 attn
    attn_k<<<dim3(32, 32), 256, 0, stream>>>(qkv, sink, attn);
    // output projection: (2048,4096) x (4096,4096) -> fp32 out
    gemm_f32in<<<dim3(32, 16), 256, 0, stream>>>(attn, wo, out, 2048, 4096, 4096, 4096, 1, 30000.0f);
}

// Round 5
// 541.164 us; speedup vs baseline: 2.9554x; 2.9554x over previous
//
#include <hip/hip_runtime.h>
#include <cstdint>
#include <cstddef>

typedef uint16_t u16;
typedef __bf16 bf16x8 __attribute__((ext_vector_type(8)));
typedef float f32x4 __attribute__((ext_vector_type(4)));
typedef u16 u16x8 __attribute__((ext_vector_type(8)));

// ---- sizes (fixed) ----
// SEQ=2048 HIDDEN=4096 NQ=32 NKV=8 HD=128 WINDOW=1024
// fp32 inputs/output; bf16 MFMA compute with pre-converted bf16 operands.
// qk row layout: [q 4096 | k 1024] stride 5120; V kept transposed (vT).

__device__ __forceinline__ u16 f2bf(float f) {
    union { float f; uint32_t i; } v; v.f = f;
    uint32_t b = v.i;
    return (u16)((b + 0x7FFFu + ((b >> 16) & 1u)) >> 16);  // RNE
}
__device__ __forceinline__ float bf2f(u16 u) {
    union { uint32_t i; float f; } v; v.i = ((uint32_t)u) << 16; return v.f;
}
__device__ __forceinline__ float nanfix(float x, float repl) {
    return (x == x && fabsf(x) < 1e30f) ? x : repl;
}
// async global->LDS, 16B per lane; lds ptr must be wave-uniform base
// (lane i lands at base + i*16) [m97/m104].
__device__ __forceinline__ void async16(const u16* g, u16* l) {
    __builtin_amdgcn_global_load_lds(
        (const __attribute__((address_space(1))) uint32_t*)g,
        (__attribute__((address_space(3))) uint32_t*)l, 16, 0, 0);
}

// ---------------- fp32 -> bf16 flat convert (n multiple of 2048*8) -----------
__global__ void cvt_k(const float* __restrict__ in, u16* __restrict__ out) {
    const size_t i = ((size_t)blockIdx.x * 256 + threadIdx.x) * 8;
    const f32x4 a = *(const f32x4*)&in[i], b = *(const f32x4*)&in[i + 4];
    u16x8 s;
    #pragma unroll
    for (int e = 0; e < 4; e++) { s[e] = f2bf(a[e]); s[4 + e] = f2bf(b[e]); }
    *(u16x8*)&out[i] = s;
}

// ---------- fp32 (R,C) -> bf16 (C,R) transpose+convert, 32x32 tiles ----------
__global__ void cvtT_k(const float* __restrict__ in, u16* __restrict__ out,
                       int R, int C) {
    __shared__ float tile[32][33];
    const int bx = blockIdx.x * 32, by = blockIdx.y * 32;
    const int tx = threadIdx.x, ty = threadIdx.y;   // (32,8)
    #pragma unroll
    for (int i = 0; i < 32; i += 8)
        tile[ty + i][tx] = in[(size_t)(by + ty + i) * C + (bx + tx)];
    __syncthreads();
    #pragma unroll
    for (int i = 0; i < 32; i += 8)
        out[(size_t)(bx + ty + i) * R + (by + tx)] = f2bf(tile[tx][ty + i]);
}

// ---------------- QKV GEMM (m97 structure): C = A(2048,4096) x BT(6144,4096)^T
// q,k cols -> qk (stride 5120); v cols -> vT[(col-5120)*2048 + row].
__global__ __launch_bounds__(256) void gemm_qkv(
    const u16* __restrict__ A, const u16* __restrict__ BT,
    u16* __restrict__ qk, u16* __restrict__ vT)
{
    alignas(16) __shared__ u16 As[128 * 32];
    alignas(16) __shared__ u16 Bs[128 * 32];
    const int tid = threadIdx.x, wave = tid >> 6;
    const int lane = tid & 63, lr = lane & 15, qd = lane >> 4;
    const int m0 = blockIdx.y * 128, n0 = blockIdx.x * 128;
    const int wm = (wave >> 1) * 64, wn = (wave & 1) * 64;
    const int K = 4096;

    f32x4 acc[4][4];
    #pragma unroll
    for (int i = 0; i < 4; i++)
        #pragma unroll
        for (int j = 0; j < 4; j++) acc[i][j] = (f32x4){0.f, 0.f, 0.f, 0.f};

    const int c0r = tid >> 2, cc = (tid & 3) * 8;   // chunk coords (32 u16/row = 4 chunks)
    const u16* Ab = A + (size_t)m0 * K;
    const u16* Bb = BT + (size_t)n0 * K;
    u16* As0 = As + wave * 512;           // (wave*64 lanes)*8 u16 = wave*512
    u16* As1 = As + 2048 + wave * 512;
    u16* Bs0 = Bs + wave * 512;
    u16* Bs1 = Bs + 2048 + wave * 512;

    for (int k0 = 0; k0 < K; k0 += 32) {
        async16(Ab + (size_t)c0r * K + k0 + cc, As0);
        async16(Ab + (size_t)(c0r + 64) * K + k0 + cc, As1);
        async16(Bb + (size_t)c0r * K + k0 + cc, Bs0);
        async16(Bb + (size_t)(c0r + 64) * K + k0 + cc, Bs1);
        __syncthreads();
        bf16x8 a[4], b[4];
        #pragma unroll
        for (int i = 0; i < 4; i++)
            a[i] = *(const bf16x8*)&As[(wm + i * 16 + lr) * 32 + qd * 8];
        #pragma unroll
        for (int i = 0; i < 4; i++)
            b[i] = *(const bf16x8*)&Bs[(wn + i * 16 + lr) * 32 + qd * 8];
        #pragma unroll
        for (int i = 0; i < 4; i++)
            #pragma unroll
            for (int j = 0; j < 4; j++)
                acc[i][j] = __builtin_amdgcn_mfma_f32_16x16x32_bf16(a[i], b[j], acc[i][j], 0, 0, 0);
        __syncthreads();
    }
    // C/D: col = lane&15, row = (lane>>4)*4 + reg [m89/m91]
    #pragma unroll
    for (int i = 0; i < 4; i++)
        #pragma unroll
        for (int j = 0; j < 4; j++) {
            const int col = n0 + wn + j * 16 + lr;
            #pragma unroll
            for (int r = 0; r < 4; r++) {
                const int row = m0 + wm + i * 16 + qd * 4 + r;
                const u16 val = f2bf(nanfix(acc[i][j][r], 1000.0f));
                if (col < 5120) qk[(size_t)row * 5120 + col] = val;
                else            vT[(size_t)(col - 5120) * 2048 + row] = val;
            }
        }
}

// ---------------- out GEMM: C_f32(2048,4096) = A(2048,4096) x BT(4096,4096)^T -
__global__ __launch_bounds__(256) void gemm_out(
    const u16* __restrict__ A, const u16* __restrict__ BT, float* __restrict__ C)
{
    alignas(16) __shared__ u16 As[128 * 32];
    alignas(16) __shared__ u16 Bs[128 * 32];
    const int tid = threadIdx.x, wave = tid >> 6;
    const int lane = tid & 63, lr = lane & 15, qd = lane >> 4;
    const int m0 = blockIdx.y * 128, n0 = blockIdx.x * 128;
    const int wm = (wave >> 1) * 64, wn = (wave & 1) * 64;
    const int K = 4096;

    f32x4 acc[4][4];
    #pragma unroll
    for (int i = 0; i < 4; i++)
        #pragma unroll
        for (int j = 0; j < 4; j++) acc[i][j] = (f32x4){0.f, 0.f, 0.f, 0.f};

    const int c0r = tid >> 2, cc = (tid & 3) * 8;
    const u16* Ab = A + (size_t)m0 * K;
    const u16* Bb = BT + (size_t)n0 * K;
    u16* As0 = As + wave * 512;
    u16* As1 = As + 2048 + wave * 512;
    u16* Bs0 = Bs + wave * 512;
    u16* Bs1 = Bs + 2048 + wave * 512;

    for (int k0 = 0; k0 < K; k0 += 32) {
        async16(Ab + (size_t)c0r * K + k0 + cc, As0);
        async16(Ab + (size_t)(c0r + 64) * K + k0 + cc, As1);
        async16(Bb + (size_t)c0r * K + k0 + cc, Bs0);
        async16(Bb + (size_t)(c0r + 64) * K + k0 + cc, Bs1);
        __syncthreads();
        bf16x8 a[4], b[4];
        #pragma unroll
        for (int i = 0; i < 4; i++)
            a[i] = *(const bf16x8*)&As[(wm + i * 16 + lr) * 32 + qd * 8];
        #pragma unroll
        for (int i = 0; i < 4; i++)
            b[i] = *(const bf16x8*)&Bs[(wn + i * 16 + lr) * 32 + qd * 8];
        #pragma unroll
        for (int i = 0; i < 4; i++)
            #pragma unroll
            for (int j = 0; j < 4; j++)
                acc[i][j] = __builtin_amdgcn_mfma_f32_16x16x32_bf16(a[i], b[j], acc[i][j], 0, 0, 0);
        __syncthreads();
    }
    #pragma unroll
    for (int i = 0; i < 4; i++)
        #pragma unroll
        for (int j = 0; j < 4; j++) {
            const int col = n0 + wn + j * 16 + lr;
            #pragma unroll
            for (int r = 0; r < 4; r++) {
                const int row = m0 + wm + i * 16 + qd * 4 + r;
                C[(size_t)row * 4096 + col] = nanfix(acc[i][j][r], 30000.0f);
            }
        }
}

// ---------------- NeoX RoPE in-place on qk (stride 5120) ----------------------
__global__ void rope_k(u16* __restrict__ qk, const int* __restrict__ positions) {
    const int s = blockIdx.x;
    const int h = blockIdx.y;   // 0..39: 32 q heads then 8 k heads
    const int t = threadIdx.x;  // pair index 0..63
    u16* base = qk + (size_t)s * 5120 + ((h < 32) ? h * 128 : 4096 + (h - 32) * 128);
    const float pos = (float)positions[s];
    const float freq = pos * exp2f(-(float)t * (19.931568569324174f / 64.f));
    const float c = cosf(freq), sn = sinf(freq);
    const float x1 = bf2f(base[t]), x2 = bf2f(base[t + 64]);
    base[t]      = f2bf(x1 * c - x2 * sn);
    base[t + 64] = f2bf(x2 * c + x1 * sn);
}

// ---------------- flash attention, window=1024, sink, GQA 4:1 ------------------
// grid (q-tile 32, head 32), 256 threads = 4 waves; wave owns 16 q-rows.
// K staged async w/ XOR chunk swizzle; V from vT w/ stride-72 LDS; Q direct.
__global__ __launch_bounds__(256) void attn_k(
    const u16* __restrict__ qk, const u16* __restrict__ vT,
    const float* __restrict__ sink, u16* __restrict__ out)
{
    alignas(16) __shared__ u16 Ks[64 * 128];    // slot = row*16 + (chunk ^ (row&15))
    alignas(16) __shared__ u16 VsT[128 * 72];   // [vd][seq], stride 72 (144B = 9x16B)
    alignas(16) __shared__ u16 Ps[4][16 * 72];

    const int h = blockIdx.y, hk = h >> 2;
    const int q0 = blockIdx.x * 64;
    const int tid = threadIdx.x, wave = tid >> 6, lane = tid & 63;
    const int lr = lane & 15, qd = lane >> 4;
    const float scaling = 0.08838834764831845f;  // 1/sqrt(128)

    // Q fragments straight from global (post-RoPE)
    bf16x8 aq[4];
    #pragma unroll
    for (int kc = 0; kc < 4; kc++)
        aq[kc] = *(const bf16x8*)&qk[(size_t)(q0 + wave * 16 + lr) * 5120 + h * 128 + kc * 32 + qd * 8];

    const float sinkv = sink[h];
    float m_run[4], l_run[4];
    #pragma unroll
    for (int r = 0; r < 4; r++) { m_run[r] = sinkv; l_run[r] = 0.f; }
    f32x4 acc_o[8];
    #pragma unroll
    for (int i = 0; i < 8; i++) acc_o[i] = (f32x4){0.f, 0.f, 0.f, 0.f};

    const int jlo = (q0 - 1023) > 0 ? (q0 - 1023) : 0;
    const int t0 = jlo >> 6, t1 = q0 >> 6;

    for (int kt = t0; kt <= t1; kt++) {
        const int j0 = kt * 64;
        __syncthreads();  // WAR: prior-iter Ks/VsT/Ps reads complete
        // K tile: 64 rows x 128 u16 = 1024 chunks of 16B, async, XOR-swizzled
        #pragma unroll
        for (int p = 0; p < 4; p++) {
            const int idx = p * 256 + tid;
            const int r = idx >> 4, cs = idx & 15, c = cs ^ (r & 15);
            async16(&qk[(size_t)(j0 + r) * 5120 + 4096 + hk * 128 + c * 8],
                    Ks + (p * 256 + wave * 64) * 8);
        }
        // V tile from vT: 128 vd-rows x 64 seq
        #pragma unroll
        for (int p = 0; p < 4; p++) {
            const int idx = p * 256 + tid;
            const int vd = idx >> 3, sc = (idx & 7) * 8;
            const u16x8 v = *(const u16x8*)&vT[(size_t)(hk * 128 + vd) * 2048 + j0 + sc];
            *(u16x8*)&VsT[vd * 72 + sc] = v;
        }
        __syncthreads();

        // S = Q K^T : per-wave 16x64
        float sv[4][4];
        #pragma unroll
        for (int nt = 0; nt < 4; nt++) {
            f32x4 s = (f32x4){0.f, 0.f, 0.f, 0.f};
            #pragma unroll
            for (int kc = 0; kc < 4; kc++) {
                const int krow = nt * 16 + lr;
                const bf16x8 bk = *(const bf16x8*)&Ks[(krow * 16 + ((kc * 4 + qd) ^ lr)) * 8];
                s = __builtin_amdgcn_mfma_f32_16x16x32_bf16(aq[kc], bk, s, 0, 0, 0);
            }
            #pragma unroll
            for (int r = 0; r < 4; r++) sv[nt][r] = s[r];
        }

        // mask + scale + rowmax (row = qd*4+r, col = nt*16+lr)
        float rmax[4] = {-1e30f, -1e30f, -1e30f, -1e30f};
        #pragma unroll
        for (int nt = 0; nt < 4; nt++) {
            const int kpos = j0 + nt * 16 + lr;
            #pragma unroll
            for (int r = 0; r < 4; r++) {
                const int qpos = q0 + wave * 16 + qd * 4 + r;
                const bool ok = (kpos <= qpos) && (qpos - kpos < 1024);
                const float x = ok ? sv[nt][r] * scaling : -1e30f;
                sv[nt][r] = x;
                rmax[r] = fmaxf(rmax[r], x);
            }
        }
        #pragma unroll
        for (int off = 1; off < 16; off <<= 1)
            #pragma unroll
            for (int r = 0; r < 4; r++)
                rmax[r] = fmaxf(rmax[r], __shfl_xor(rmax[r], off, 64));

        float alpha[4], rsum[4];
        #pragma unroll
        for (int r = 0; r < 4; r++) {
            const float mnew = fmaxf(m_run[r], rmax[r]);
            alpha[r] = __expf(m_run[r] - mnew);
            m_run[r] = mnew;
            rsum[r] = 0.f;
        }
        #pragma unroll
        for (int nt = 0; nt < 4; nt++)
            #pragma unroll
            for (int r = 0; r < 4; r++) {
                const float p = __expf(sv[nt][r] - m_run[r]);
                sv[nt][r] = p;
                rsum[r] += p;
            }
        #pragma unroll
        for (int off = 1; off < 16; off <<= 1)
            #pragma unroll
            for (int r = 0; r < 4; r++)
                rsum[r] += __shfl_xor(rsum[r], off, 64);
        #pragma unroll
        for (int r = 0; r < 4; r++)
            l_run[r] = l_run[r] * alpha[r] + rsum[r];

        // P (C-layout) -> LDS bridge (stride 72); barrier before A-layout read
        #pragma unroll
        for (int nt = 0; nt < 4; nt++)
            #pragma unroll
            for (int r = 0; r < 4; r++)
                Ps[wave][(qd * 4 + r) * 72 + nt * 16 + lr] = f2bf(sv[nt][r]);

        #pragma unroll
        for (int i = 0; i < 8; i++)
            #pragma unroll
            for (int r = 0; r < 4; r++) acc_o[i][r] *= alpha[r];

        __syncthreads();

        bf16x8 pa[2];
        #pragma unroll
        for (int kc = 0; kc < 2; kc++)
            pa[kc] = *(const bf16x8*)&Ps[wave][lr * 72 + kc * 32 + qd * 8];

        #pragma unroll
        for (int nt = 0; nt < 8; nt++)
            #pragma unroll
            for (int kc = 0; kc < 2; kc++) {
                const bf16x8 bv = *(const bf16x8*)&VsT[(nt * 16 + lr) * 72 + kc * 32 + qd * 8];
                acc_o[nt] = __builtin_amdgcn_mfma_f32_16x16x32_bf16(pa[kc], bv, acc_o[nt], 0, 0, 0);
            }
    }

    float invd[4];
    #pragma unroll
    for (int r = 0; r < 4; r++)
        invd[r] = 1.f / (l_run[r] + __expf(sinkv - m_run[r]));
    #pragma unroll
    for (int nt = 0; nt < 8; nt++) {
        const int col = h * 128 + nt * 16 + lr;
        #pragma unroll
        for (int r = 0; r < 4; r++) {
            const int row = q0 + wave * 16 + qd * 4 + r;
            out[(size_t)row * 4096 + col] = f2bf(nanfix(acc_o[nt][r] * invd[r], 8.0f));
        }
    }
}

extern "C" void kernel_launch(void* const* d_in, const int* in_sizes, int n_in,
                              void* d_out, int out_size, void* d_ws, size_t ws_size,
                              hipStream_t stream)
{
    (void)in_sizes; (void)n_in; (void)out_size; (void)ws_size;
    const float* hidden    = (const float*)d_in[0];
    const int*   positions = (const int*)d_in[1];
    const float* wq   = (const float*)d_in[2];
    const float* wk   = (const float*)d_in[3];
    const float* wv   = (const float*)d_in[4];
    const float* wo   = (const float*)d_in[5];
    const float* sink = (const float*)d_in[6];
    float* out = (float*)d_out;

    // Workspace (88 MB peak):
    //  [0,16M)   hiddenB (2048x4096 bf16)      -- dead after gemm_qkv
    //  [16,64M)  wqkvT (6144x4096 bf16)        -- dead after gemm_qkv
    //  [64,84M)  qk (2048x5120 bf16)
    //  [84,88M)  vT (1024x2048 bf16)
    //  reuse:    [0,32M) woT (4096x4096 bf16), [32,48M) attnB (2048x4096 bf16)
    char* ws = (char*)d_ws;
    u16* hiddenB = (u16*)(ws);
    u16* wqkvT   = (u16*)(ws + (size_t)16777216);
    u16* qk      = (u16*)(ws + (size_t)67108864);
    u16* vT      = (u16*)(ws + (size_t)88080384);
    u16* woT     = (u16*)(ws);
    u16* attnB   = (u16*)(ws + (size_t)33554432);

    // convert / transpose to bf16 (bandwidth passes)
    cvt_k <<<4096, 256, 0, stream>>>(hidden, hiddenB);
    cvtT_k<<<dim3(128, 128), dim3(32, 8), 0, stream>>>(wq, wqkvT, 4096, 4096);
    cvtT_k<<<dim3(32, 128),  dim3(32, 8), 0, stream>>>(wk, wqkvT + (size_t)4096 * 4096, 4096, 1024);
    cvtT_k<<<dim3(32, 128),  dim3(32, 8), 0, stream>>>(wv, wqkvT + (size_t)5120 * 4096, 4096, 1024);

    // fused QKV projection (q,k -> qk; v -> vT)
    gemm_qkv<<<dim3(48, 16), 256, 0, stream>>>(hiddenB, wqkvT, qk, vT);

    // wqkvT/hiddenB dead -> wo transpose into their space
    cvtT_k<<<dim3(128, 128), dim3(32, 8), 0, stream>>>(wo, woT, 4096, 4096);

    rope_k<<<dim3(2048, 40), 64, 0, stream>>>(qk, positions);
    attn_k<<<dim3(32, 32), 256, 0, stream>>>(qk, vT, sink, attnB);
    gemm_out<<<dim3(32, 16), 256, 0, stream>>>(attnB, woT, out);
}